// Round 8
// baseline (789.968 us; speedup 1.0000x reference)
//
#include <hip/hip_runtime.h>

#define NB 100000
#define NG 20000
#define EL 1000000
#define EX 200000
#define NSEG (2 * NB + NG)   // concatenated CSR rows: [line->bus | g2b->bus | b2g->gen]
#define TILE 2048
#define NTILES ((NSEG + TILE - 1) / TILE)   // 108 (must be <= 256)
#define KP 16                // k per staging phase (combine kernels)
#define TST 66               // LDS stride of [k][row] tile: bank=(2k+r)%32 -> 2-way max
#define CST 65               // epilogue transpose stride
#define CBUF (64 * CST)      // 4160 floats = 16.6 KB shared buffer

static __device__ __forceinline__ int uni(int x) { return __builtin_amdgcn_readfirstlane(x); }

// ---- int degree count: deg[dst[i]] += 1 ----
__global__ void counti_kernel(const int* __restrict__ dst, int* __restrict__ deg, int E) {
    int i = blockIdx.x * blockDim.x + threadIdx.x;
    if (i < E) atomicAdd(&deg[dst[i]], 1);
}

// ---- hierarchical scan, stage 1: per-tile sums (coalesced) ----
__global__ __launch_bounds__(256) void scan_part_kernel(const int* __restrict__ deg,
                                                        int* __restrict__ partial, int n) {
    __shared__ int ls[256];
    const int t = threadIdx.x;
    const int base = blockIdx.x * TILE;
    int s = 0;
    for (int i = t; i < TILE; i += 256) {
        int idx = base + i;
        s += (idx < n) ? deg[idx] : 0;
    }
    ls[t] = s;
    __syncthreads();
    for (int d = 128; d > 0; d >>= 1) {
        if (t < d) ls[t] += ls[t + d];
        __syncthreads();
    }
    if (t == 0) partial[blockIdx.x] = ls[0];
}

// ---- stage 2: single-block exclusive scan of partials; writes off[n]=total ----
__global__ __launch_bounds__(256) void scan_top_kernel(int* __restrict__ partial,
                                                       int* __restrict__ off, int nparts, int n) {
    __shared__ int ls[256];
    const int t = threadIdx.x;
    ls[t] = (t < nparts) ? partial[t] : 0;
    __syncthreads();
    for (int d = 1; d < 256; d <<= 1) {
        int x = (t >= d) ? ls[t - d] : 0;
        __syncthreads();
        ls[t] += x;
        __syncthreads();
    }
    if (t < nparts) partial[t] = (t == 0) ? 0 : ls[t - 1];
    if (t == 255) off[n] = ls[255];
}

// ---- stage 3: per-tile exclusive scan + global base; writes off and cursor ----
__global__ __launch_bounds__(256) void scan_write_kernel(const int* __restrict__ deg,
                                                         const int* __restrict__ partial,
                                                         int* __restrict__ off,
                                                         int* __restrict__ cur, int n) {
    __shared__ int ls[256];
    const int t = threadIdx.x;
    const int b0 = blockIdx.x * TILE + t * 8;
    int local[8];
    int s = 0;
#pragma unroll
    for (int j = 0; j < 8; ++j) {
        int idx = b0 + j;
        local[j] = (idx < n) ? deg[idx] : 0;
        s += local[j];
    }
    ls[t] = s;
    __syncthreads();
    for (int d = 1; d < 256; d <<= 1) {
        int x = (t >= d) ? ls[t - d] : 0;
        __syncthreads();
        ls[t] += x;
        __syncthreads();
    }
    int run = partial[blockIdx.x] + ((t == 0) ? 0 : ls[t - 1]);
#pragma unroll
    for (int j = 0; j < 8; ++j) {
        int idx = b0 + j;
        if (idx < n) { off[idx] = run; cur[idx] = run; run += local[j]; }
    }
}

// ---- CSR fill: elist[cursor[base+dst]++] = src ----
__global__ void fill_kernel(const int* __restrict__ src, const int* __restrict__ dst,
                            int* __restrict__ cursor, int* __restrict__ elist, int E, int base) {
    int i = blockIdx.x * blockDim.x + threadIdx.x;
    if (i < E) {
        int pos = atomicAdd(&cursor[base + dst[i]], 1);
        elist[pos] = src[i];
    }
}

// ---- mean over CSR segment with 4-wide load pipelining ----
static __device__ __forceinline__ float seg_mean(const float* __restrict__ h,
                                                 const int* __restrict__ elist,
                                                 int s0, int e0, int lane) {
    float s = 0.f;
    int e = s0;
    for (; e + 4 <= e0; e += 4) {
        int i0 = elist[e], i1 = elist[e + 1], i2 = elist[e + 2], i3 = elist[e + 3];
        float v0 = h[(size_t)i0 * 64 + lane];
        float v1 = h[(size_t)i1 * 64 + lane];
        float v2 = h[(size_t)i2 * 64 + lane];
        float v3 = h[(size_t)i3 * 64 + lane];
        s += v0 + v1 + v2 + v3;
    }
    for (; e < e0; ++e) s += h[(size_t)elist[e] * 64 + lane];
    return s / fmaxf((float)(e0 - s0), 1.f);
}

// ---- bus-node aggregation ----
__global__ __launch_bounds__(256) void aggr_bus_kernel(
    const float* __restrict__ hb, const float* __restrict__ hg,
    const int* __restrict__ off, const int* __restrict__ elist,
    float* __restrict__ Aline, float* __restrict__ Ag2b)
{
    const int lane = threadIdx.x & 63;
    int b = uni(blockIdx.x * 4 + (threadIdx.x >> 6));
    if (b >= NB) return;
    Aline[(size_t)b * 64 + lane] = seg_mean(hb, elist, off[b], off[b + 1], lane);
    Ag2b[(size_t)b * 64 + lane]  = seg_mean(hg, elist, off[NB + b], off[NB + b + 1], lane);
}

// ---- gen-node aggregation ----
__global__ __launch_bounds__(256) void aggr_gen_kernel(
    const float* __restrict__ hb, const int* __restrict__ off, const int* __restrict__ elist,
    float* __restrict__ Ab2g)
{
    const int lane = threadIdx.x & 63;
    int g = uni(blockIdx.x * 4 + (threadIdx.x >> 6));
    if (g >= NG) return;
    Ab2g[(size_t)g * 64 + lane] = seg_mean(hb, elist, off[2 * NB + g], off[2 * NB + g + 1], lane);
}

// ---- bus combine, k-phased tiled GEMM: out = relu(h@W0 + Al@W1 + Ag@W2 + b).
//      R7 (full 50 KB 3-tile LDS) -> 3 blocks/CU, 25% occupancy, VALUBusy 25%.
//      Now: 4 phases of 16 k through ONE 16.6 KB buffer (aliased with epilogue
//      transpose), register-prefetch of next phase before compute -> ~8 blocks/CU. ----
__global__ __launch_bounds__(256) void combine_bus_kernel(
    const float* __restrict__ h, const float* __restrict__ Al, const float* __restrict__ Ag,
    const float* __restrict__ W0, const float* __restrict__ W1, const float* __restrict__ W2,
    const float* __restrict__ bias, float* __restrict__ out, int n)
{
    __shared__ float buf[CBUF];
    float* t0 = buf;
    float* t1 = buf + KP * TST;
    float* t2 = buf + 2 * KP * TST;

    const int t = threadIdx.x;
    const int base = blockIdx.x * 64;
    const int r = t >> 2;             // tile row 0..63
    const int kq = (t & 3) * 4;       // k-quad within phase: 0,4,8,12
    const bool rok = (base + r) < n;
    const size_t grow = (size_t)(base + r) * 64;

    float4 f0 = {0, 0, 0, 0}, f1 = f0, f2 = f0;
    if (rok) {
        f0 = *(const float4*)(h  + grow + kq);
        f1 = *(const float4*)(Al + grow + kq);
        f2 = *(const float4*)(Ag + grow + kq);
    }

    const int lane = t & 63;
    const int j0 = uni((t >> 6) << 4);   // wave-uniform output-col base
    float acc[16];
#pragma unroll
    for (int jj = 0; jj < 16; ++jj) acc[jj] = 0.f;

    for (int p = 0; p < 4; ++p) {
        __syncthreads();   // previous compute done -> buffer free
        t0[(kq + 0) * TST + r] = f0.x; t0[(kq + 1) * TST + r] = f0.y;
        t0[(kq + 2) * TST + r] = f0.z; t0[(kq + 3) * TST + r] = f0.w;
        t1[(kq + 0) * TST + r] = f1.x; t1[(kq + 1) * TST + r] = f1.y;
        t1[(kq + 2) * TST + r] = f1.z; t1[(kq + 3) * TST + r] = f1.w;
        t2[(kq + 0) * TST + r] = f2.x; t2[(kq + 1) * TST + r] = f2.y;
        t2[(kq + 2) * TST + r] = f2.z; t2[(kq + 3) * TST + r] = f2.w;
        __syncthreads();
        if (p < 3 && rok) {            // prefetch next phase; waits land at next write
            int kg = (p + 1) * KP + kq;
            f0 = *(const float4*)(h  + grow + kg);
            f1 = *(const float4*)(Al + grow + kg);
            f2 = *(const float4*)(Ag + grow + kg);
        }
#pragma unroll
        for (int kk = 0; kk < KP; ++kk) {
            const int k = p * KP + kk;
            const float hk = t0[kk * TST + lane];
            const float ak = t1[kk * TST + lane];
            const float gk = t2[kk * TST + lane];
            const float* __restrict__ w0 = W0 + k * 64 + j0;
            const float* __restrict__ w1 = W1 + k * 64 + j0;
            const float* __restrict__ w2 = W2 + k * 64 + j0;
#pragma unroll
            for (int jj = 0; jj < 16; ++jj)
                acc[jj] += hk * w0[jj] + ak * w1[jj] + gk * w2[jj];
        }
    }

    // epilogue: bias+relu, transpose through LDS, coalesced float4 store
    __syncthreads();
#pragma unroll
    for (int jj = 0; jj < 16; ++jj)
        buf[(j0 + jj) * CST + lane] = fmaxf(acc[jj] + bias[j0 + jj], 0.f);
    __syncthreads();
#pragma unroll
    for (int i = 0; i < 4; ++i) {
        int flat = i * 1024 + t * 4;
        int rr = flat >> 6, c = flat & 63;
        if (base + rr < n) {
            float4 o4 = { buf[(c + 0) * CST + rr], buf[(c + 1) * CST + rr],
                          buf[(c + 2) * CST + rr], buf[(c + 3) * CST + rr] };
            *(float4*)(out + (size_t)(base + rr) * 64 + c) = o4;
        }
    }
}

// ---- gen combine, same structure, 2 matrices: out = relu(h@W0 + A@W1 + b) ----
__global__ __launch_bounds__(256) void combine_gen_kernel(
    const float* __restrict__ h, const float* __restrict__ A,
    const float* __restrict__ W0, const float* __restrict__ W1,
    const float* __restrict__ bias, float* __restrict__ out, int n)
{
    __shared__ float buf[CBUF];
    float* t0 = buf;
    float* t1 = buf + KP * TST;

    const int t = threadIdx.x;
    const int base = blockIdx.x * 64;
    const int r = t >> 2;
    const int kq = (t & 3) * 4;
    const bool rok = (base + r) < n;
    const size_t grow = (size_t)(base + r) * 64;

    float4 f0 = {0, 0, 0, 0}, f1 = f0;
    if (rok) {
        f0 = *(const float4*)(h + grow + kq);
        f1 = *(const float4*)(A + grow + kq);
    }

    const int lane = t & 63;
    const int j0 = uni((t >> 6) << 4);
    float acc[16];
#pragma unroll
    for (int jj = 0; jj < 16; ++jj) acc[jj] = 0.f;

    for (int p = 0; p < 4; ++p) {
        __syncthreads();
        t0[(kq + 0) * TST + r] = f0.x; t0[(kq + 1) * TST + r] = f0.y;
        t0[(kq + 2) * TST + r] = f0.z; t0[(kq + 3) * TST + r] = f0.w;
        t1[(kq + 0) * TST + r] = f1.x; t1[(kq + 1) * TST + r] = f1.y;
        t1[(kq + 2) * TST + r] = f1.z; t1[(kq + 3) * TST + r] = f1.w;
        __syncthreads();
        if (p < 3 && rok) {
            int kg = (p + 1) * KP + kq;
            f0 = *(const float4*)(h + grow + kg);
            f1 = *(const float4*)(A + grow + kg);
        }
#pragma unroll
        for (int kk = 0; kk < KP; ++kk) {
            const int k = p * KP + kk;
            const float hk = t0[kk * TST + lane];
            const float ak = t1[kk * TST + lane];
            const float* __restrict__ w0 = W0 + k * 64 + j0;
            const float* __restrict__ w1 = W1 + k * 64 + j0;
#pragma unroll
            for (int jj = 0; jj < 16; ++jj)
                acc[jj] += hk * w0[jj] + ak * w1[jj];
        }
    }

    __syncthreads();
#pragma unroll
    for (int jj = 0; jj < 16; ++jj)
        buf[(j0 + jj) * CST + lane] = fmaxf(acc[jj] + bias[j0 + jj], 0.f);
    __syncthreads();
#pragma unroll
    for (int i = 0; i < 4; ++i) {
        int flat = i * 1024 + t * 4;
        int rr = flat >> 6, c = flat & 63;
        if (base + rr < n) {
            float4 o4 = { buf[(c + 0) * CST + rr], buf[(c + 1) * CST + rr],
                          buf[(c + 2) * CST + rr], buf[(c + 3) * CST + rr] };
            *(float4*)(out + (size_t)(base + rr) * 64 + c) = o4;
        }
    }
}

// ---- column-sum pool ----
__global__ __launch_bounds__(256) void pool_kernel(
    const float* __restrict__ h, int n, float* __restrict__ pool)
{
    int lane = threadIdx.x & 63;
    int w = threadIdx.x >> 6;
    float s = 0.f;
    for (int row = blockIdx.x * 4 + w; row < n; row += gridDim.x * 4)
        s += h[(size_t)row * 64 + lane];
    __shared__ float red[256];
    red[threadIdx.x] = s;
    __syncthreads();
    if (threadIdx.x < 64) {
        float t = red[threadIdx.x] + red[threadIdx.x + 64] + red[threadIdx.x + 128] + red[threadIdx.x + 192];
        atomicAdd(&pool[lane], t);
    }
}

// ---- head: out = relu(g @ Wh + bh) @ Wo + bo ----
__global__ void head_kernel(const float* __restrict__ pool,
                            const float* __restrict__ Wh, const float* __restrict__ bh,
                            const float* __restrict__ Wo, const float* __restrict__ bo,
                            float* __restrict__ out)
{
    __shared__ float g[128];
    __shared__ float hid[64];
    int t = threadIdx.x;  // 128 threads
    g[t] = pool[t];
    __syncthreads();
    if (t < 64) {
        float a = bh[t];
        for (int i = 0; i < 128; ++i) a += g[i] * Wh[i * 64 + t];
        hid[t] = fmaxf(a, 0.f);
    }
    __syncthreads();
    if (t < 16) {
        float a = bo[t];
        for (int j = 0; j < 64; ++j) a += hid[j] * Wo[j * 16 + t];
        out[t] = a;
    }
}

extern "C" void kernel_launch(void* const* d_in, const int* in_sizes, int n_in,
                              void* d_out, int out_size, void* d_ws, size_t ws_size,
                              hipStream_t stream)
{
    const float* x_bus   = (const float*)d_in[0];
    const float* x_gen   = (const float*)d_in[1];
    const int* line_src  = (const int*)d_in[2];
    const int* line_dst  = (const int*)d_in[3];
    const int* g2b_src   = (const int*)d_in[4];
    const int* g2b_dst   = (const int*)d_in[5];
    const int* b2g_src   = (const int*)d_in[6];
    const int* b2g_dst   = (const int*)d_in[7];
    const float* Wsb[2]  = {(const float*)d_in[8],  (const float*)d_in[15]};
    const float* Wsg[2]  = {(const float*)d_in[9],  (const float*)d_in[16]};
    const float* Wl[2]   = {(const float*)d_in[10], (const float*)d_in[17]};
    const float* Wg2b[2] = {(const float*)d_in[11], (const float*)d_in[18]};
    const float* Wb2g[2] = {(const float*)d_in[12], (const float*)d_in[19]};
    const float* bsb[2]  = {(const float*)d_in[13], (const float*)d_in[20]};
    const float* bsg[2]  = {(const float*)d_in[14], (const float*)d_in[21]};
    const float* Wh = (const float*)d_in[22];
    const float* bh = (const float*)d_in[23];
    const float* Wo = (const float*)d_in[24];
    const float* bo = (const float*)d_in[25];
    (void)in_sizes; (void)n_in; (void)out_size; (void)ws_size;

    char* wsB = (char*)d_ws;
    size_t o = 0;
    auto alloc_f = [&](size_t nelem) { float* p = (float*)(wsB + o); o += nelem * sizeof(float); return p; };
    auto alloc_i = [&](size_t nelem) { int*   p = (int*)  (wsB + o); o += nelem * sizeof(int);   return p; };

    float* H1b   = alloc_f((size_t)NB * 64);
    float* H1g   = alloc_f((size_t)NG * 64);
    float* H2b   = alloc_f((size_t)NB * 64);
    float* H2g   = alloc_f((size_t)NG * 64);
    float* Aline = alloc_f((size_t)NB * 64);
    float* Ag2b  = alloc_f((size_t)NB * 64);
    float* Ab2g  = alloc_f((size_t)NG * 64);
    int*   elist = alloc_i(EL + 2 * EX);
    int*   deg   = alloc_i(NSEG);
    int*   off   = alloc_i(NSEG + 1);
    int*   cur   = alloc_i(NSEG);
    int*   part  = alloc_i(256);
    float* pool  = alloc_f(128);

    // ---- CSR build ----
    hipMemsetAsync(deg, 0, NSEG * sizeof(int), stream);
    hipMemsetAsync(pool, 0, 128 * sizeof(float), stream);
    counti_kernel<<<(EL + 255) / 256, 256, 0, stream>>>(line_dst, deg, EL);
    counti_kernel<<<(EX + 255) / 256, 256, 0, stream>>>(g2b_dst, deg + NB, EX);
    counti_kernel<<<(EX + 255) / 256, 256, 0, stream>>>(b2g_dst, deg + 2 * NB, EX);
    scan_part_kernel<<<NTILES, 256, 0, stream>>>(deg, part, NSEG);
    scan_top_kernel<<<1, 256, 0, stream>>>(part, off, NTILES, NSEG);
    scan_write_kernel<<<NTILES, 256, 0, stream>>>(deg, part, off, cur, NSEG);
    fill_kernel<<<(EL + 255) / 256, 256, 0, stream>>>(line_src, line_dst, cur, elist, EL, 0);
    fill_kernel<<<(EX + 255) / 256, 256, 0, stream>>>(g2b_src, g2b_dst, cur, elist, EX, NB);
    fill_kernel<<<(EX + 255) / 256, 256, 0, stream>>>(b2g_src, b2g_dst, cur, elist, EX, 2 * NB);

    const int gbB = (NB + 3) / 4, gbG = (NG + 3) / 4;
    const int tbB = (NB + 63) / 64, tbG = (NG + 63) / 64;

    // ---- layer 0 ----
    aggr_bus_kernel<<<gbB, 256, 0, stream>>>(x_bus, x_gen, off, elist, Aline, Ag2b);
    aggr_gen_kernel<<<gbG, 256, 0, stream>>>(x_bus, off, elist, Ab2g);
    combine_bus_kernel<<<tbB, 256, 0, stream>>>(x_bus, Aline, Ag2b, Wsb[0], Wl[0], Wg2b[0], bsb[0], H1b, NB);
    combine_gen_kernel<<<tbG, 256, 0, stream>>>(x_gen, Ab2g, Wsg[0], Wb2g[0], bsg[0], H1g, NG);

    // ---- layer 1 ----
    aggr_bus_kernel<<<gbB, 256, 0, stream>>>(H1b, H1g, off, elist, Aline, Ag2b);
    aggr_gen_kernel<<<gbG, 256, 0, stream>>>(H1b, off, elist, Ab2g);
    combine_bus_kernel<<<tbB, 256, 0, stream>>>(H1b, Aline, Ag2b, Wsb[1], Wl[1], Wg2b[1], bsb[1], H2b, NB);
    combine_gen_kernel<<<tbG, 256, 0, stream>>>(H1g, Ab2g, Wsg[1], Wb2g[1], bsg[1], H2g, NG);

    // ---- pool + head ----
    pool_kernel<<<512, 256, 0, stream>>>(H2b, NB, pool);
    pool_kernel<<<512, 256, 0, stream>>>(H2g, NG, pool + 64);
    head_kernel<<<1, 128, 0, stream>>>(pool, Wh, bh, Wo, bo, (float*)d_out);
}

// Round 9
// 625.482 us; speedup vs baseline: 1.2630x; 1.2630x over previous
//
#include <hip/hip_runtime.h>

#define NB 100000
#define NG 20000
#define EL 1000000
#define EX 200000
#define NSEG (2 * NB + NG)   // concatenated CSR rows: [line->bus | g2b->bus | b2g->gen]
#define TILE 2048
#define NTILES ((NSEG + TILE - 1) / TILE)   // 108 (must be <= 256)
#define TSH 65               // ushort stride of bf16 [k][row] tiles
#define CST 65               // float stride of epilogue transpose buffer

static __device__ __forceinline__ int uni(int x) { return __builtin_amdgcn_readfirstlane(x); }

static __device__ __forceinline__ unsigned short f2bf(float x) {   // RNE f32->bf16
    unsigned u = __float_as_uint(x);
    u += 0x7FFF + ((u >> 16) & 1);
    return (unsigned short)(u >> 16);
}
static __device__ __forceinline__ float bf2f(unsigned short s) {
    return __uint_as_float(((unsigned)s) << 16);
}

// ---- int degree count ----
__global__ void counti_kernel(const int* __restrict__ dst, int* __restrict__ deg, int E) {
    int i = blockIdx.x * blockDim.x + threadIdx.x;
    if (i < E) atomicAdd(&deg[dst[i]], 1);
}

// ---- hierarchical scan ----
__global__ __launch_bounds__(256) void scan_part_kernel(const int* __restrict__ deg,
                                                        int* __restrict__ partial, int n) {
    __shared__ int ls[256];
    const int t = threadIdx.x;
    const int base = blockIdx.x * TILE;
    int s = 0;
    for (int i = t; i < TILE; i += 256) {
        int idx = base + i;
        s += (idx < n) ? deg[idx] : 0;
    }
    ls[t] = s;
    __syncthreads();
    for (int d = 128; d > 0; d >>= 1) {
        if (t < d) ls[t] += ls[t + d];
        __syncthreads();
    }
    if (t == 0) partial[blockIdx.x] = ls[0];
}

__global__ __launch_bounds__(256) void scan_top_kernel(int* __restrict__ partial,
                                                       int* __restrict__ off, int nparts, int n) {
    __shared__ int ls[256];
    const int t = threadIdx.x;
    ls[t] = (t < nparts) ? partial[t] : 0;
    __syncthreads();
    for (int d = 1; d < 256; d <<= 1) {
        int x = (t >= d) ? ls[t - d] : 0;
        __syncthreads();
        ls[t] += x;
        __syncthreads();
    }
    if (t < nparts) partial[t] = (t == 0) ? 0 : ls[t - 1];
    if (t == 255) off[n] = ls[255];
}

__global__ __launch_bounds__(256) void scan_write_kernel(const int* __restrict__ deg,
                                                         const int* __restrict__ partial,
                                                         int* __restrict__ off,
                                                         int* __restrict__ cur, int n) {
    __shared__ int ls[256];
    const int t = threadIdx.x;
    const int b0 = blockIdx.x * TILE + t * 8;
    int local[8];
    int s = 0;
#pragma unroll
    for (int j = 0; j < 8; ++j) {
        int idx = b0 + j;
        local[j] = (idx < n) ? deg[idx] : 0;
        s += local[j];
    }
    ls[t] = s;
    __syncthreads();
    for (int d = 1; d < 256; d <<= 1) {
        int x = (t >= d) ? ls[t - d] : 0;
        __syncthreads();
        ls[t] += x;
        __syncthreads();
    }
    int run = partial[blockIdx.x] + ((t == 0) ? 0 : ls[t - 1]);
#pragma unroll
    for (int j = 0; j < 8; ++j) {
        int idx = b0 + j;
        if (idx < n) { off[idx] = run; cur[idx] = run; run += local[j]; }
    }
}

// ---- CSR fill ----
__global__ void fill_kernel(const int* __restrict__ src, const int* __restrict__ dst,
                            int* __restrict__ cursor, int* __restrict__ elist, int E, int base) {
    int i = blockIdx.x * blockDim.x + threadIdx.x;
    if (i < E) {
        int pos = atomicAdd(&cursor[base + dst[i]], 1);
        elist[pos] = src[i];
    }
}

// ---- mean over CSR segment, 8 gathers in flight ----
static __device__ __forceinline__ float seg_mean(const float* __restrict__ h,
                                                 const int* __restrict__ elist,
                                                 int s0, int e0, int lane) {
    float s = 0.f;
    int e = s0;
    for (; e + 8 <= e0; e += 8) {
        int i0 = elist[e],     i1 = elist[e + 1], i2 = elist[e + 2], i3 = elist[e + 3];
        int i4 = elist[e + 4], i5 = elist[e + 5], i6 = elist[e + 6], i7 = elist[e + 7];
        float v0 = h[(size_t)i0 * 64 + lane], v1 = h[(size_t)i1 * 64 + lane];
        float v2 = h[(size_t)i2 * 64 + lane], v3 = h[(size_t)i3 * 64 + lane];
        float v4 = h[(size_t)i4 * 64 + lane], v5 = h[(size_t)i5 * 64 + lane];
        float v6 = h[(size_t)i6 * 64 + lane], v7 = h[(size_t)i7 * 64 + lane];
        s += ((v0 + v1) + (v2 + v3)) + ((v4 + v5) + (v6 + v7));
    }
    for (; e + 2 <= e0; e += 2) {
        int i0 = elist[e], i1 = elist[e + 1];
        s += h[(size_t)i0 * 64 + lane] + h[(size_t)i1 * 64 + lane];
    }
    if (e < e0) s += h[(size_t)elist[e] * 64 + lane];
    return s / fmaxf((float)(e0 - s0), 1.f);
}

// ---- merged aggregation: waves [0,NB) do bus rows (line + g2b), [NB,NB+NG) do gen rows ----
__global__ __launch_bounds__(256) void aggr_all_kernel(
    const float* __restrict__ hb, const float* __restrict__ hg,
    const int* __restrict__ off, const int* __restrict__ elist,
    float* __restrict__ Aline, float* __restrict__ Ag2b, float* __restrict__ Ab2g)
{
    const int lane = threadIdx.x & 63;
    int w = uni(blockIdx.x * 4 + (threadIdx.x >> 6));
    if (w < NB) {
        Aline[(size_t)w * 64 + lane] = seg_mean(hb, elist, off[w], off[w + 1], lane);
        Ag2b[(size_t)w * 64 + lane]  = seg_mean(hg, elist, off[NB + w], off[NB + w + 1], lane);
    } else if (w < NB + NG) {
        int g = w - NB;
        Ab2g[(size_t)g * 64 + lane] = seg_mean(hb, elist, off[2 * NB + g], off[2 * NB + g + 1], lane);
    }
}

// ---- bus combine: out = relu(h@W0 + Al@W1 + Ag@W2 + b).
//      R7 structure (single-barrier k-loop — R8's phased rewrite regressed 2x, don't).
//      bf16 LDS staging: 50->26 KB => 6 blocks/CU (R7 was 3, s_load weight latency exposed).
//      pool != nullptr (layer 1): skip global store, column-reduce + atomicAdd to pool. ----
__global__ __launch_bounds__(256) void combine_bus_kernel(
    const float* __restrict__ h, const float* __restrict__ Al, const float* __restrict__ Ag,
    const float* __restrict__ W0, const float* __restrict__ W1, const float* __restrict__ W2,
    const float* __restrict__ bias, float* __restrict__ out, float* __restrict__ pool, int n)
{
    __shared__ __attribute__((aligned(16))) unsigned short tiles[3][64 * TSH]; // 24.96 KB
    __shared__ float red[256];
    float* fbuf = (float*)&tiles[0][0];          // 16.6 KB epilogue alias (after barrier)
    const int t = threadIdx.x;
    const int base = blockIdx.x * 64;

    // stage: coalesced float4 global reads -> transposed bf16 LDS writes
#pragma unroll
    for (int i = 0; i < 4; ++i) {
        int flat = i * 1024 + t * 4;
        int r = flat >> 6, c = flat & 63;
        if (base + r < n) {
            const float4 fh = *(const float4*)(h  + (size_t)(base + r) * 64 + c);
            const float4 fa = *(const float4*)(Al + (size_t)(base + r) * 64 + c);
            const float4 fg = *(const float4*)(Ag + (size_t)(base + r) * 64 + c);
            tiles[0][(c + 0) * TSH + r] = f2bf(fh.x); tiles[0][(c + 1) * TSH + r] = f2bf(fh.y);
            tiles[0][(c + 2) * TSH + r] = f2bf(fh.z); tiles[0][(c + 3) * TSH + r] = f2bf(fh.w);
            tiles[1][(c + 0) * TSH + r] = f2bf(fa.x); tiles[1][(c + 1) * TSH + r] = f2bf(fa.y);
            tiles[1][(c + 2) * TSH + r] = f2bf(fa.z); tiles[1][(c + 3) * TSH + r] = f2bf(fa.w);
            tiles[2][(c + 0) * TSH + r] = f2bf(fg.x); tiles[2][(c + 1) * TSH + r] = f2bf(fg.y);
            tiles[2][(c + 2) * TSH + r] = f2bf(fg.z); tiles[2][(c + 3) * TSH + r] = f2bf(fg.w);
        }
    }
    __syncthreads();

    const int lane = t & 63;                 // = row within tile
    const int j0 = uni((t >> 6) << 4);       // wave-uniform output-col base
    float acc[16];
#pragma unroll
    for (int jj = 0; jj < 16; ++jj) acc[jj] = 0.f;

    for (int k = 0; k < 64; ++k) {
        float hk = bf2f(tiles[0][k * TSH + lane]);
        float ak = bf2f(tiles[1][k * TSH + lane]);
        float gk = bf2f(tiles[2][k * TSH + lane]);
        const float* __restrict__ w0 = W0 + k * 64 + j0;
        const float* __restrict__ w1 = W1 + k * 64 + j0;
        const float* __restrict__ w2 = W2 + k * 64 + j0;
#pragma unroll
        for (int jj = 0; jj < 16; ++jj)
            acc[jj] += hk * w0[jj] + ak * w1[jj] + gk * w2[jj];
    }
    __syncthreads();

    // epilogue: bias+relu (invalid rows forced to 0 so fused pool is exact)
    const bool rowok = (base + lane) < n;
#pragma unroll
    for (int jj = 0; jj < 16; ++jj)
        fbuf[(j0 + jj) * CST + lane] = rowok ? fmaxf(acc[jj] + bias[j0 + jj], 0.f) : 0.f;
    __syncthreads();

    if (pool) {
        int col = t >> 2, q = t & 3;
        float s = 0.f;
#pragma unroll
        for (int i = 0; i < 16; ++i) s += fbuf[col * CST + q * 16 + i];
        red[t] = s;
        __syncthreads();
        if (q == 0) atomicAdd(&pool[col], red[t] + red[t + 1] + red[t + 2] + red[t + 3]);
    } else {
#pragma unroll
        for (int i = 0; i < 4; ++i) {
            int flat = i * 1024 + t * 4;
            int rr = flat >> 6, c = flat & 63;
            if (base + rr < n) {
                float4 o4 = { fbuf[(c + 0) * CST + rr], fbuf[(c + 1) * CST + rr],
                              fbuf[(c + 2) * CST + rr], fbuf[(c + 3) * CST + rr] };
                *(float4*)(out + (size_t)(base + rr) * 64 + c) = o4;
            }
        }
    }
}

// ---- gen combine: out = relu(h@W0 + A@W1 + b), same structure, 2 tiles ----
__global__ __launch_bounds__(256) void combine_gen_kernel(
    const float* __restrict__ h, const float* __restrict__ A,
    const float* __restrict__ W0, const float* __restrict__ W1,
    const float* __restrict__ bias, float* __restrict__ out, float* __restrict__ pool, int n)
{
    __shared__ __attribute__((aligned(16))) unsigned short tiles[2][64 * TSH]; // 16.6 KB
    __shared__ float red[256];
    float* fbuf = (float*)&tiles[0][0];
    const int t = threadIdx.x;
    const int base = blockIdx.x * 64;
#pragma unroll
    for (int i = 0; i < 4; ++i) {
        int flat = i * 1024 + t * 4;
        int r = flat >> 6, c = flat & 63;
        if (base + r < n) {
            const float4 fh = *(const float4*)(h + (size_t)(base + r) * 64 + c);
            const float4 fa = *(const float4*)(A + (size_t)(base + r) * 64 + c);
            tiles[0][(c + 0) * TSH + r] = f2bf(fh.x); tiles[0][(c + 1) * TSH + r] = f2bf(fh.y);
            tiles[0][(c + 2) * TSH + r] = f2bf(fh.z); tiles[0][(c + 3) * TSH + r] = f2bf(fh.w);
            tiles[1][(c + 0) * TSH + r] = f2bf(fa.x); tiles[1][(c + 1) * TSH + r] = f2bf(fa.y);
            tiles[1][(c + 2) * TSH + r] = f2bf(fa.z); tiles[1][(c + 3) * TSH + r] = f2bf(fa.w);
        }
    }
    __syncthreads();
    const int lane = t & 63;
    const int j0 = uni((t >> 6) << 4);
    float acc[16];
#pragma unroll
    for (int jj = 0; jj < 16; ++jj) acc[jj] = 0.f;
    for (int k = 0; k < 64; ++k) {
        float hk = bf2f(tiles[0][k * TSH + lane]);
        float ak = bf2f(tiles[1][k * TSH + lane]);
        const float* __restrict__ w0 = W0 + k * 64 + j0;
        const float* __restrict__ w1 = W1 + k * 64 + j0;
#pragma unroll
        for (int jj = 0; jj < 16; ++jj)
            acc[jj] += hk * w0[jj] + ak * w1[jj];
    }
    __syncthreads();
    const bool rowok = (base + lane) < n;
#pragma unroll
    for (int jj = 0; jj < 16; ++jj)
        fbuf[(j0 + jj) * CST + lane] = rowok ? fmaxf(acc[jj] + bias[j0 + jj], 0.f) : 0.f;
    __syncthreads();
    if (pool) {
        int col = t >> 2, q = t & 3;
        float s = 0.f;
#pragma unroll
        for (int i = 0; i < 16; ++i) s += fbuf[col * CST + q * 16 + i];
        red[t] = s;
        __syncthreads();
        if (q == 0) atomicAdd(&pool[col], red[t] + red[t + 1] + red[t + 2] + red[t + 3]);
    } else {
#pragma unroll
        for (int i = 0; i < 4; ++i) {
            int flat = i * 1024 + t * 4;
            int rr = flat >> 6, c = flat & 63;
            if (base + rr < n) {
                float4 o4 = { fbuf[(c + 0) * CST + rr], fbuf[(c + 1) * CST + rr],
                              fbuf[(c + 2) * CST + rr], fbuf[(c + 3) * CST + rr] };
                *(float4*)(out + (size_t)(base + rr) * 64 + c) = o4;
            }
        }
    }
}

// ---- head: out = relu(g @ Wh + bh) @ Wo + bo ----
__global__ void head_kernel(const float* __restrict__ pool,
                            const float* __restrict__ Wh, const float* __restrict__ bh,
                            const float* __restrict__ Wo, const float* __restrict__ bo,
                            float* __restrict__ out)
{
    __shared__ float g[128];
    __shared__ float hid[64];
    int t = threadIdx.x;  // 128 threads
    g[t] = pool[t];
    __syncthreads();
    if (t < 64) {
        float a = bh[t];
        for (int i = 0; i < 128; ++i) a += g[i] * Wh[i * 64 + t];
        hid[t] = fmaxf(a, 0.f);
    }
    __syncthreads();
    if (t < 16) {
        float a = bo[t];
        for (int j = 0; j < 64; ++j) a += hid[j] * Wo[j * 16 + t];
        out[t] = a;
    }
}

extern "C" void kernel_launch(void* const* d_in, const int* in_sizes, int n_in,
                              void* d_out, int out_size, void* d_ws, size_t ws_size,
                              hipStream_t stream)
{
    const float* x_bus   = (const float*)d_in[0];
    const float* x_gen   = (const float*)d_in[1];
    const int* line_src  = (const int*)d_in[2];
    const int* line_dst  = (const int*)d_in[3];
    const int* g2b_src   = (const int*)d_in[4];
    const int* g2b_dst   = (const int*)d_in[5];
    const int* b2g_src   = (const int*)d_in[6];
    const int* b2g_dst   = (const int*)d_in[7];
    const float* Wsb[2]  = {(const float*)d_in[8],  (const float*)d_in[15]};
    const float* Wsg[2]  = {(const float*)d_in[9],  (const float*)d_in[16]};
    const float* Wl[2]   = {(const float*)d_in[10], (const float*)d_in[17]};
    const float* Wg2b[2] = {(const float*)d_in[11], (const float*)d_in[18]};
    const float* Wb2g[2] = {(const float*)d_in[12], (const float*)d_in[19]};
    const float* bsb[2]  = {(const float*)d_in[13], (const float*)d_in[20]};
    const float* bsg[2]  = {(const float*)d_in[14], (const float*)d_in[21]};
    const float* Wh = (const float*)d_in[22];
    const float* bh = (const float*)d_in[23];
    const float* Wo = (const float*)d_in[24];
    const float* bo = (const float*)d_in[25];
    (void)in_sizes; (void)n_in; (void)out_size; (void)ws_size;

    char* wsB = (char*)d_ws;
    size_t o = 0;
    auto alloc_f = [&](size_t nelem) { float* p = (float*)(wsB + o); o += nelem * sizeof(float); return p; };
    auto alloc_i = [&](size_t nelem) { int*   p = (int*)  (wsB + o); o += nelem * sizeof(int);   return p; };

    float* H1b   = alloc_f((size_t)NB * 64);
    float* H1g   = alloc_f((size_t)NG * 64);
    float* Aline = alloc_f((size_t)NB * 64);
    float* Ag2b  = alloc_f((size_t)NB * 64);
    float* Ab2g  = alloc_f((size_t)NG * 64);
    int*   elist = alloc_i(EL + 2 * EX);
    int*   deg   = alloc_i(NSEG);
    int*   off   = alloc_i(NSEG + 1);
    int*   cur   = alloc_i(NSEG);
    int*   part  = alloc_i(256);
    float* pool  = alloc_f(128);

    // ---- CSR build ----
    hipMemsetAsync(deg, 0, NSEG * sizeof(int), stream);
    hipMemsetAsync(pool, 0, 128 * sizeof(float), stream);
    counti_kernel<<<(EL + 255) / 256, 256, 0, stream>>>(line_dst, deg, EL);
    counti_kernel<<<(EX + 255) / 256, 256, 0, stream>>>(g2b_dst, deg + NB, EX);
    counti_kernel<<<(EX + 255) / 256, 256, 0, stream>>>(b2g_dst, deg + 2 * NB, EX);
    scan_part_kernel<<<NTILES, 256, 0, stream>>>(deg, part, NSEG);
    scan_top_kernel<<<1, 256, 0, stream>>>(part, off, NTILES, NSEG);
    scan_write_kernel<<<NTILES, 256, 0, stream>>>(deg, part, off, cur, NSEG);
    fill_kernel<<<(EL + 255) / 256, 256, 0, stream>>>(line_src, line_dst, cur, elist, EL, 0);
    fill_kernel<<<(EX + 255) / 256, 256, 0, stream>>>(g2b_src, g2b_dst, cur, elist, EX, NB);
    fill_kernel<<<(EX + 255) / 256, 256, 0, stream>>>(b2g_src, b2g_dst, cur, elist, EX, 2 * NB);

    const int gaA = (NB + NG + 3) / 4;
    const int tbB = (NB + 63) / 64, tbG = (NG + 63) / 64;

    // ---- layer 0 ----
    aggr_all_kernel<<<gaA, 256, 0, stream>>>(x_bus, x_gen, off, elist, Aline, Ag2b, Ab2g);
    combine_bus_kernel<<<tbB, 256, 0, stream>>>(x_bus, Aline, Ag2b, Wsb[0], Wl[0], Wg2b[0], bsb[0], H1b, nullptr, NB);
    combine_gen_kernel<<<tbG, 256, 0, stream>>>(x_gen, Ab2g, Wsg[0], Wb2g[0], bsg[0], H1g, nullptr, NG);

    // ---- layer 1 (outputs only pooled -> fused column-sum, no H2 buffers) ----
    aggr_all_kernel<<<gaA, 256, 0, stream>>>(H1b, H1g, off, elist, Aline, Ag2b, Ab2g);
    combine_bus_kernel<<<tbB, 256, 0, stream>>>(H1b, Aline, Ag2b, Wsb[1], Wl[1], Wg2b[1], bsb[1], Aline, pool, NB);
    combine_gen_kernel<<<tbG, 256, 0, stream>>>(H1g, Ab2g, Wsg[1], Wb2g[1], bsg[1], Ab2g, pool + 64, NG);

    // ---- head ----
    head_kernel<<<1, 128, 0, stream>>>(pool, Wh, bh, Wo, bo, (float*)d_out);
}

// Round 10
// 517.798 us; speedup vs baseline: 1.5256x; 1.2080x over previous
//
#include <hip/hip_runtime.h>

#define NB 100000
#define NG 20000
#define EL 1000000
#define EX 200000
#define NSEG (2 * NB + NG)   // concatenated CSR rows: [line->bus | g2b->bus | b2g->gen]
#define TILE 2048
#define NTILES ((NSEG + TILE - 1) / TILE)   // 108 (must be <= 256)
#define WROW 72              // Wt row stride (ushorts): 144 B = 16-aligned, 2-way banks
#define WMAT (64 * WROW)     // 4608 ushorts per 64x64 matrix
#define AST 200              // A-tile row stride (ushorts): 400 B = 16-aligned, 2-way banks

typedef __attribute__((ext_vector_type(8))) short bf16x8;
typedef __attribute__((ext_vector_type(4))) float f32x4;

static __device__ __forceinline__ int uni(int x) { return __builtin_amdgcn_readfirstlane(x); }

static __device__ __forceinline__ unsigned short f2bf(float x) {   // RNE f32->bf16
    unsigned u = __float_as_uint(x);
    u += 0x7FFF + ((u >> 16) & 1);
    return (unsigned short)(u >> 16);
}

// ---- int degree count ----
__global__ void counti_kernel(const int* __restrict__ dst, int* __restrict__ deg, int E) {
    int i = blockIdx.x * blockDim.x + threadIdx.x;
    if (i < E) atomicAdd(&deg[dst[i]], 1);
}

// ---- hierarchical scan ----
__global__ __launch_bounds__(256) void scan_part_kernel(const int* __restrict__ deg,
                                                        int* __restrict__ partial, int n) {
    __shared__ int ls[256];
    const int t = threadIdx.x;
    const int base = blockIdx.x * TILE;
    int s = 0;
    for (int i = t; i < TILE; i += 256) {
        int idx = base + i;
        s += (idx < n) ? deg[idx] : 0;
    }
    ls[t] = s;
    __syncthreads();
    for (int d = 128; d > 0; d >>= 1) {
        if (t < d) ls[t] += ls[t + d];
        __syncthreads();
    }
    if (t == 0) partial[blockIdx.x] = ls[0];
}

__global__ __launch_bounds__(256) void scan_top_kernel(int* __restrict__ partial,
                                                       int* __restrict__ off, int nparts, int n) {
    __shared__ int ls[256];
    const int t = threadIdx.x;
    ls[t] = (t < nparts) ? partial[t] : 0;
    __syncthreads();
    for (int d = 1; d < 256; d <<= 1) {
        int x = (t >= d) ? ls[t - d] : 0;
        __syncthreads();
        ls[t] += x;
        __syncthreads();
    }
    if (t < nparts) partial[t] = (t == 0) ? 0 : ls[t - 1];
    if (t == 255) off[n] = ls[255];
}

__global__ __launch_bounds__(256) void scan_write_kernel(const int* __restrict__ deg,
                                                         const int* __restrict__ partial,
                                                         int* __restrict__ off,
                                                         int* __restrict__ cur, int n) {
    __shared__ int ls[256];
    const int t = threadIdx.x;
    const int b0 = blockIdx.x * TILE + t * 8;
    int local[8];
    int s = 0;
#pragma unroll
    for (int j = 0; j < 8; ++j) {
        int idx = b0 + j;
        local[j] = (idx < n) ? deg[idx] : 0;
        s += local[j];
    }
    ls[t] = s;
    __syncthreads();
    for (int d = 1; d < 256; d <<= 1) {
        int x = (t >= d) ? ls[t - d] : 0;
        __syncthreads();
        ls[t] += x;
        __syncthreads();
    }
    int run = partial[blockIdx.x] + ((t == 0) ? 0 : ls[t - 1]);
#pragma unroll
    for (int j = 0; j < 8; ++j) {
        int idx = b0 + j;
        if (idx < n) { off[idx] = run; cur[idx] = run; run += local[j]; }
    }
}

// ---- CSR fill ----
__global__ void fill_kernel(const int* __restrict__ src, const int* __restrict__ dst,
                            int* __restrict__ cursor, int* __restrict__ elist, int E, int base) {
    int i = blockIdx.x * blockDim.x + threadIdx.x;
    if (i < E) {
        int pos = atomicAdd(&cursor[base + dst[i]], 1);
        elist[pos] = src[i];
    }
}

// ---- weight prep: Wt[n*72+k] = bf16(W[k*64+n]) for 10 matrices (one block each) ----
struct WPrep { const float* src[10]; unsigned short* dst[10]; };
__global__ __launch_bounds__(256) void wprep_kernel(WPrep p) {
    const float* __restrict__ s = p.src[blockIdx.x];
    unsigned short* __restrict__ d = p.dst[blockIdx.x];
    for (int idx = threadIdx.x; idx < 4096; idx += 256) {
        int k = idx >> 6, nn = idx & 63;
        d[nn * WROW + k] = f2bf(s[idx]);
    }
}

// ---- mean over CSR segment, 8 gathers in flight ----
static __device__ __forceinline__ float seg_mean(const float* __restrict__ h,
                                                 const int* __restrict__ elist,
                                                 int s0, int e0, int lane) {
    float s = 0.f;
    int e = s0;
    for (; e + 8 <= e0; e += 8) {
        int i0 = elist[e],     i1 = elist[e + 1], i2 = elist[e + 2], i3 = elist[e + 3];
        int i4 = elist[e + 4], i5 = elist[e + 5], i6 = elist[e + 6], i7 = elist[e + 7];
        float v0 = h[(size_t)i0 * 64 + lane], v1 = h[(size_t)i1 * 64 + lane];
        float v2 = h[(size_t)i2 * 64 + lane], v3 = h[(size_t)i3 * 64 + lane];
        float v4 = h[(size_t)i4 * 64 + lane], v5 = h[(size_t)i5 * 64 + lane];
        float v6 = h[(size_t)i6 * 64 + lane], v7 = h[(size_t)i7 * 64 + lane];
        s += ((v0 + v1) + (v2 + v3)) + ((v4 + v5) + (v6 + v7));
    }
    for (; e + 2 <= e0; e += 2) {
        int i0 = elist[e], i1 = elist[e + 1];
        s += h[(size_t)i0 * 64 + lane] + h[(size_t)i1 * 64 + lane];
    }
    if (e < e0) s += h[(size_t)elist[e] * 64 + lane];
    return s / fmaxf((float)(e0 - s0), 1.f);
}

// ---- merged aggregation: waves [0,NB) do bus rows (line + g2b), [NB,NB+NG) do gen rows ----
__global__ __launch_bounds__(256) void aggr_all_kernel(
    const float* __restrict__ hb, const float* __restrict__ hg,
    const int* __restrict__ off, const int* __restrict__ elist,
    float* __restrict__ Aline, float* __restrict__ Ag2b, float* __restrict__ Ab2g)
{
    const int lane = threadIdx.x & 63;
    int w = uni(blockIdx.x * 4 + (threadIdx.x >> 6));
    if (w < NB) {
        Aline[(size_t)w * 64 + lane] = seg_mean(hb, elist, off[w], off[w + 1], lane);
        Ag2b[(size_t)w * 64 + lane]  = seg_mean(hg, elist, off[NB + w], off[NB + w + 1], lane);
    } else if (w < NB + NG) {
        int g = w - NB;
        Ab2g[(size_t)g * 64 + lane] = seg_mean(hb, elist, off[2 * NB + g], off[2 * NB + g + 1], lane);
    }
}

// ---- MFMA combine: out = relu([h|A1|A2] @ Wt^T + bias), K = nmat*64.
//      R9 VALU combine: 218k cyc/CU elapsed vs 37k issue — s_load weight latency bound,
//      and fp32-VALU has a 71 µs chip-wide FMA-issue floor. MFMA (16x16x32 bf16) cuts
//      k-loop issue ~9x and removes scalar weight loads (weights = LDS B-frags).
//      A-tile row-major bf16 (no transpose: A-frag lane reads 8 contiguous k);
//      Wt pre-transposed [n][k] by wprep. C/D: col=lane&15, row=quad*4+reg (guide §3).
//      pool != nullptr: fused column-sum (per-element row guard) -> LDS -> atomicAdd. ----
__global__ __launch_bounds__(256) void combine_mfma_kernel(
    const float* __restrict__ h, const float* __restrict__ A1, const float* __restrict__ A2,
    const unsigned short* __restrict__ Wt, const float* __restrict__ bias,
    float* __restrict__ out, float* __restrict__ pool, int n, int nmat)
{
    __shared__ __attribute__((aligned(16))) unsigned short Atile[64 * AST]; // 25.6 KB
    __shared__ __attribute__((aligned(16))) unsigned short Wtile[3 * WMAT]; // 27.6 KB
    __shared__ float pred[64];
    const int t = threadIdx.x;
    const int base = blockIdx.x * 64;

    if (t < 64) pred[t] = 0.f;

    // stage A (row-major bf16): k 0..63 = h, 64..127 = A1, 128..191 = A2
#pragma unroll
    for (int i = 0; i < 4; ++i) {
        int flat = i * 1024 + t * 4;
        int r = flat >> 6, c = flat & 63;
        bool ok = (base + r) < n;
        float4 f0 = {0, 0, 0, 0}, f1 = f0, f2 = f0;
        size_t g = (size_t)(base + r) * 64 + c;
        if (ok) {
            f0 = *(const float4*)(h + g);
            f1 = *(const float4*)(A1 + g);
            if (nmat == 3) f2 = *(const float4*)(A2 + g);
        }
        ushort4 u;
        u.x = f2bf(f0.x); u.y = f2bf(f0.y); u.z = f2bf(f0.z); u.w = f2bf(f0.w);
        *(ushort4*)&Atile[r * AST + c] = u;
        u.x = f2bf(f1.x); u.y = f2bf(f1.y); u.z = f2bf(f1.z); u.w = f2bf(f1.w);
        *(ushort4*)&Atile[r * AST + 64 + c] = u;
        if (nmat == 3) {
            u.x = f2bf(f2.x); u.y = f2bf(f2.y); u.z = f2bf(f2.z); u.w = f2bf(f2.w);
            *(ushort4*)&Atile[r * AST + 128 + c] = u;
        }
    }
    // stage Wt (already bf16 [n][k], straight copy)
    {
        const int nv = nmat * (WMAT / 4);
        const ushort4* __restrict__ src = (const ushort4*)Wt;
        ushort4* dst = (ushort4*)Wtile;
        for (int idx = t; idx < nv; idx += 256) dst[idx] = src[idx];
    }
    __syncthreads();

    const int lane = t & 63;
    const int w = t >> 6;          // wave -> output rows [16w, 16w+16)
    const int l15 = lane & 15;
    const int q = lane >> 4;
    f32x4 acc[4];
#pragma unroll
    for (int c = 0; c < 4; ++c) acc[c] = (f32x4){0.f, 0.f, 0.f, 0.f};

    const int ksteps = nmat * 2;
    for (int ks = 0; ks < ksteps; ++ks) {
        bf16x8 av = *(const bf16x8*)&Atile[(w * 16 + l15) * AST + ks * 32 + q * 8];
#pragma unroll
        for (int c = 0; c < 4; ++c) {
            bf16x8 bv = *(const bf16x8*)&Wtile[(ks >> 1) * WMAT + (c * 16 + l15) * WROW + (ks & 1) * 32 + q * 8];
            acc[c] = __builtin_amdgcn_mfma_f32_16x16x32_bf16(av, bv, acc[c], 0, 0, 0);
        }
    }

    if (pool == nullptr) {
#pragma unroll
        for (int c = 0; c < 4; ++c) {
            const int col = c * 16 + l15;
            const float bv = bias[col];
#pragma unroll
            for (int reg = 0; reg < 4; ++reg) {
                int row = base + w * 16 + q * 4 + reg;
                if (row < n) out[(size_t)row * 64 + col] = fmaxf(acc[c][reg] + bv, 0.f);
            }
        }
    } else {
#pragma unroll
        for (int c = 0; c < 4; ++c) {
            const int col = c * 16 + l15;
            const float bv = bias[col];
            float s = 0.f;
#pragma unroll
            for (int reg = 0; reg < 4; ++reg) {
                int row = base + w * 16 + q * 4 + reg;
                if (row < n) s += fmaxf(acc[c][reg] + bv, 0.f);
            }
            atomicAdd(&pred[col], s);
        }
        __syncthreads();
        if (t < 64) atomicAdd(&pool[t], pred[t]);
    }
}

// ---- head: out = relu(g @ Wh + bh) @ Wo + bo ----
__global__ void head_kernel(const float* __restrict__ pool,
                            const float* __restrict__ Wh, const float* __restrict__ bh,
                            const float* __restrict__ Wo, const float* __restrict__ bo,
                            float* __restrict__ out)
{
    __shared__ float g[128];
    __shared__ float hid[64];
    int t = threadIdx.x;  // 128 threads
    g[t] = pool[t];
    __syncthreads();
    if (t < 64) {
        float a = bh[t];
        for (int i = 0; i < 128; ++i) a += g[i] * Wh[i * 64 + t];
        hid[t] = fmaxf(a, 0.f);
    }
    __syncthreads();
    if (t < 16) {
        float a = bo[t];
        for (int j = 0; j < 64; ++j) a += hid[j] * Wo[j * 16 + t];
        out[t] = a;
    }
}

extern "C" void kernel_launch(void* const* d_in, const int* in_sizes, int n_in,
                              void* d_out, int out_size, void* d_ws, size_t ws_size,
                              hipStream_t stream)
{
    const float* x_bus   = (const float*)d_in[0];
    const float* x_gen   = (const float*)d_in[1];
    const int* line_src  = (const int*)d_in[2];
    const int* line_dst  = (const int*)d_in[3];
    const int* g2b_src   = (const int*)d_in[4];
    const int* g2b_dst   = (const int*)d_in[5];
    const int* b2g_src   = (const int*)d_in[6];
    const int* b2g_dst   = (const int*)d_in[7];
    const float* Wsb[2]  = {(const float*)d_in[8],  (const float*)d_in[15]};
    const float* Wsg[2]  = {(const float*)d_in[9],  (const float*)d_in[16]};
    const float* Wl[2]   = {(const float*)d_in[10], (const float*)d_in[17]};
    const float* Wg2b[2] = {(const float*)d_in[11], (const float*)d_in[18]};
    const float* Wb2g[2] = {(const float*)d_in[12], (const float*)d_in[19]};
    const float* bsb[2]  = {(const float*)d_in[13], (const float*)d_in[20]};
    const float* bsg[2]  = {(const float*)d_in[14], (const float*)d_in[21]};
    const float* Wh = (const float*)d_in[22];
    const float* bh = (const float*)d_in[23];
    const float* Wo = (const float*)d_in[24];
    const float* bo = (const float*)d_in[25];
    (void)in_sizes; (void)n_in; (void)out_size; (void)ws_size;

    char* wsB = (char*)d_ws;
    size_t o = 0;
    auto alloc_f = [&](size_t nelem) { o = (o + 15) & ~(size_t)15; float* p = (float*)(wsB + o); o += nelem * sizeof(float); return p; };
    auto alloc_i = [&](size_t nelem) { o = (o + 15) & ~(size_t)15; int* p = (int*)(wsB + o); o += nelem * sizeof(int); return p; };
    auto alloc_u = [&](size_t nelem) { o = (o + 15) & ~(size_t)15; unsigned short* p = (unsigned short*)(wsB + o); o += nelem * sizeof(unsigned short); return p; };

    float* H1b   = alloc_f((size_t)NB * 64);
    float* H1g   = alloc_f((size_t)NG * 64);
    float* Aline = alloc_f((size_t)NB * 64);
    float* Ag2b  = alloc_f((size_t)NB * 64);
    float* Ab2g  = alloc_f((size_t)NG * 64);
    int*   elist = alloc_i(EL + 2 * EX);
    int*   deg   = alloc_i(NSEG);
    int*   off   = alloc_i(NSEG + 1);
    int*   cur   = alloc_i(NSEG);
    int*   part  = alloc_i(256);
    float* pool  = alloc_f(128);
    unsigned short* WtBus[2] = { alloc_u(3 * WMAT), alloc_u(3 * WMAT) };
    unsigned short* WtGen[2] = { alloc_u(2 * WMAT), alloc_u(2 * WMAT) };

    // ---- weight prep (independent of CSR) ----
    WPrep wp;
    for (int l = 0; l < 2; ++l) {
        wp.src[l * 5 + 0] = Wsb[l];  wp.dst[l * 5 + 0] = WtBus[l] + 0 * WMAT;
        wp.src[l * 5 + 1] = Wl[l];   wp.dst[l * 5 + 1] = WtBus[l] + 1 * WMAT;
        wp.src[l * 5 + 2] = Wg2b[l]; wp.dst[l * 5 + 2] = WtBus[l] + 2 * WMAT;
        wp.src[l * 5 + 3] = Wsg[l];  wp.dst[l * 5 + 3] = WtGen[l] + 0 * WMAT;
        wp.src[l * 5 + 4] = Wb2g[l]; wp.dst[l * 5 + 4] = WtGen[l] + 1 * WMAT;
    }
    wprep_kernel<<<10, 256, 0, stream>>>(wp);

    // ---- CSR build ----
    hipMemsetAsync(deg, 0, NSEG * sizeof(int), stream);
    hipMemsetAsync(pool, 0, 128 * sizeof(float), stream);
    counti_kernel<<<(EL + 255) / 256, 256, 0, stream>>>(line_dst, deg, EL);
    counti_kernel<<<(EX + 255) / 256, 256, 0, stream>>>(g2b_dst, deg + NB, EX);
    counti_kernel<<<(EX + 255) / 256, 256, 0, stream>>>(b2g_dst, deg + 2 * NB, EX);
    scan_part_kernel<<<NTILES, 256, 0, stream>>>(deg, part, NSEG);
    scan_top_kernel<<<1, 256, 0, stream>>>(part, off, NTILES, NSEG);
    scan_write_kernel<<<NTILES, 256, 0, stream>>>(deg, part, off, cur, NSEG);
    fill_kernel<<<(EL + 255) / 256, 256, 0, stream>>>(line_src, line_dst, cur, elist, EL, 0);
    fill_kernel<<<(EX + 255) / 256, 256, 0, stream>>>(g2b_src, g2b_dst, cur, elist, EX, NB);
    fill_kernel<<<(EX + 255) / 256, 256, 0, stream>>>(b2g_src, b2g_dst, cur, elist, EX, 2 * NB);

    const int gaA = (NB + NG + 3) / 4;
    const int tbB = (NB + 63) / 64, tbG = (NG + 63) / 64;

    // ---- layer 0 ----
    aggr_all_kernel<<<gaA, 256, 0, stream>>>(x_bus, x_gen, off, elist, Aline, Ag2b, Ab2g);
    combine_mfma_kernel<<<tbB, 256, 0, stream>>>(x_bus, Aline, Ag2b, WtBus[0], bsb[0], H1b, nullptr, NB, 3);
    combine_mfma_kernel<<<tbG, 256, 0, stream>>>(x_gen, Ab2g, nullptr, WtGen[0], bsg[0], H1g, nullptr, NG, 2);

    // ---- layer 1 (outputs only pooled -> fused column-sum) ----
    aggr_all_kernel<<<gaA, 256, 0, stream>>>(H1b, H1g, off, elist, Aline, Ag2b, Ab2g);
    combine_mfma_kernel<<<tbB, 256, 0, stream>>>(H1b, Aline, Ag2b, WtBus[1], bsb[1], H1b, pool, NB, 3);
    combine_mfma_kernel<<<tbG, 256, 0, stream>>>(H1g, Ab2g, nullptr, WtGen[1], bsg[1], H1g, pool + 64, NG, 2);

    // ---- head ----
    head_kernel<<<1, 128, 0, stream>>>(pool, Wh, bh, Wo, bo, (float*)d_out);
}